// Round 18
// baseline (386.531 us; speedup 1.0000x reference)
//
#include <hip/hip_runtime.h>
#include <hip/hip_fp16.h>

constexpr int Bn = 2, C = 21, H = 256, W = 256, HW = H * W;
constexpr int GP = 3;                       // quad-pairs (8 channels per 16B)
constexpr int TW = 32, TH = 16, NT = 1024;  // output tile / block size
constexpr int HALO = 10;                    // 5 iterations x 2-halo
constexpr int EH = TH + 2 * HALO;           // 36
constexpr int EW = TW + 2 * HALO;           // 52
constexpr int NEC = EH * EW;                // 1872

// Normalized spatial gaussian (sigma=5): exp(-(dy^2+dx^2)/50)/S, S=23.1036923.
__device__ constexpr float SKN[25] = {
    0.03688346f, 0.03916421f, 0.03995538f, 0.03916421f, 0.03688346f,
    0.03916421f, 0.04158598f, 0.04242608f, 0.04158598f, 0.03916421f,
    0.03995538f, 0.04242608f, 0.04328314f, 0.04242608f, 0.03995538f,
    0.03916421f, 0.04158598f, 0.04242608f, 0.04158598f, 0.03916421f,
    0.03688346f, 0.03916421f, 0.03995538f, 0.03916421f, 0.03688346f};

union H2U { __half2 h; unsigned int u; };

__device__ __forceinline__ unsigned int packh2(float a, float b) {
    H2U u; u.h = __floats2half2_rn(a, b); return u.u;
}
__device__ __forceinline__ float3 dec3(unsigned int urg, unsigned int ubz) {
    H2U a; a.u = urg; const float2 rg = __half22float2(a.h);
    H2U b; b.u = ubz; const float2 bz = __half22float2(b.h);
    return make_float3(rg.x, rg.y, bz.x);
}

// Bilateral weight for kernel row R, col CC vs center c (identity folded at
// the window center: spatial gaussian sigma=0.1 is a delta).
template <int R, int CC>
__device__ __forceinline__ unsigned int wcalc(const float3& p, const float3& c) {
    const float d0 = p.x - c.x, d1 = p.y - c.y, d2 = p.z - c.z;
    float wv = SKN[R * 5 + CC] * __expf(-50.f * (d0 * d0 + d1 * d1 + d2 * d2));
    if (R == 2 && CC == 2) wv += 1.0f;
    return packh2(wv, wv);
}

// ---------------------------------------------------------------------------
// One tap row (kernel row R) for a horizontal cell pair (ex0, ex0+1).
// 6 consecutive cells per g serve both cells' 5 taps (rolling 2-reg window).
// Weights streamed one img position at a time (liveness = 1 float3).
// ---------------------------------------------------------------------------
template <int R>
__device__ __forceinline__ void row_taps(
        int ly, int ex0, const uint2* __restrict__ simgh,
        const uint4 (*__restrict__ bufQ)[EH][EW],
        const float3& c0, const float3& c1,
        __half2 (&a0)[GP][4], __half2 (&a1)[GP][4]) {
    const int base = ly * EW + ex0;
    const uint4 iA = *reinterpret_cast<const uint4*>(simgh + base - 2);
    const uint4 iB = *reinterpret_cast<const uint4*>(simgh + base);
    const uint4 iC = *reinterpret_cast<const uint4*>(simgh + base + 2);
    unsigned int w0[5], w1[5];
    {
        float3 p;
        p = dec3(iA.x, iA.y); w0[0] = wcalc<R, 0>(p, c0);
        p = dec3(iA.z, iA.w); w0[1] = wcalc<R, 1>(p, c0); w1[0] = wcalc<R, 0>(p, c1);
        p = dec3(iB.x, iB.y); w0[2] = wcalc<R, 2>(p, c0); w1[1] = wcalc<R, 1>(p, c1);
        p = dec3(iB.z, iB.w); w0[3] = wcalc<R, 3>(p, c0); w1[2] = wcalc<R, 2>(p, c1);
        p = dec3(iC.x, iC.y); w0[4] = wcalc<R, 4>(p, c0); w1[3] = wcalc<R, 3>(p, c1);
        p = dec3(iC.z, iC.w);                             w1[4] = wcalc<R, 4>(p, c1);
    }
#pragma unroll
    for (int g = 0; g < GP; ++g) {
        const uint4* qrow = &bufQ[g][ly][ex0 - 2];
        uint4 qa = qrow[0];
#pragma unroll
        for (int c = 0; c < 5; ++c) {
            const uint4 qb = qrow[c + 1];
            H2U wv; wv.u = w0[c];
            H2U q0, q1, q2, q3;
            q0.u = qa.x; q1.u = qa.y; q2.u = qa.z; q3.u = qa.w;
            a0[g][0] = __hfma2(wv.h, q0.h, a0[g][0]);
            a0[g][1] = __hfma2(wv.h, q1.h, a0[g][1]);
            a0[g][2] = __hfma2(wv.h, q2.h, a0[g][2]);
            a0[g][3] = __hfma2(wv.h, q3.h, a0[g][3]);
            H2U wu; wu.u = w1[c];
            q0.u = qb.x; q1.u = qb.y; q2.u = qb.z; q3.u = qb.w;
            a1[g][0] = __hfma2(wu.h, q0.h, a1[g][0]);
            a1[g][1] = __hfma2(wu.h, q1.h, a1[g][1]);
            a1[g][2] = __hfma2(wu.h, q2.h, a1[g][2]);
            a1[g][3] = __hfma2(wu.h, q3.h, a1[g][3]);
            qa = qb;
        }
    }
}

// ---------------------------------------------------------------------------
// Compat + softmax + output for one cell (acc consumed; z[24] transient).
// ---------------------------------------------------------------------------
template <bool FINAL>
__device__ __forceinline__ void finish_cell(
        int fast, const float* __restrict__ lgp, const float* __restrict__ scm,
        const __half2 (&acc)[GP][4], float* __restrict__ qo, uint4 (&nq)[GP]) {
    float z[24];
    if (fast) {                        // compat == -I: z = logits + m
#pragma unroll
        for (int g = 0; g < GP; ++g)
#pragma unroll
            for (int j = 0; j < 4; ++j) {
                const float2 f = __half22float2(acc[g][j]);
                const int c = 8 * g + 2 * j;
                z[c]     = (c     < C) ? lgp[(size_t)c * HW] + f.x       : -1e30f;
                z[c + 1] = (c + 1 < C) ? lgp[(size_t)(c + 1) * HW] + f.y : -1e30f;
            }
    } else {                           // general matvec, thread-local
        float m[24];
#pragma unroll
        for (int g = 0; g < GP; ++g)
#pragma unroll
            for (int j = 0; j < 4; ++j) {
                const float2 f = __half22float2(acc[g][j]);
                m[8 * g + 2 * j + 0] = f.x;
                m[8 * g + 2 * j + 1] = f.y;
            }
#pragma unroll
        for (int c = 0; c < 24; ++c) {
            if (c < C) {
                float pw = 0.f;
#pragma unroll
                for (int j = 0; j < C; ++j) pw += scm[c * C + j] * m[j];
                z[c] = lgp[(size_t)c * HW] - pw;
            } else z[c] = -1e30f;
        }
    }
    float mx = -1e30f;
#pragma unroll
    for (int c = 0; c < C; ++c) mx = fmaxf(mx, z[c]);
    float s = 0.f;
#pragma unroll
    for (int c = 0; c < 24; ++c) {
        z[c] = (c < C) ? __expf(z[c] - mx) : 0.f;
        if (c < C) s += z[c];
    }
    const float inv = 1.f / s;
    if (FINAL) {
#pragma unroll
        for (int c = 0; c < C; ++c) qo[(size_t)c * HW] = z[c] * inv;
    } else {
#pragma unroll
        for (int g = 0; g < GP; ++g)
            nq[g] = make_uint4(
                packh2(z[8 * g + 0] * inv, z[8 * g + 1] * inv),
                packh2(z[8 * g + 2] * inv, z[8 * g + 3] * inv),
                packh2(z[8 * g + 4] * inv, z[8 * g + 5] * inv),
                packh2(z[8 * g + 6] * inv, z[8 * g + 7] * inv));
    }
}

// ---------------------------------------------------------------------------
// One mean-field iteration over the shrinking region; horizontal pair per
// thread (all margins give <= 768 pairs < NT: single strip, no arrays).
// ---------------------------------------------------------------------------
template <int MARGIN, bool FINAL>
__device__ __forceinline__ void mf_iter(
        int tid, int b, int y0, int x0, int fast,
        const float* __restrict__ lgb, const float* __restrict__ scm,
        uint4 (*bufQ)[EH][EW], const uint2* __restrict__ simgh,
        float* __restrict__ outp) {
    constexpr int HT_ = EH - 2 * MARGIN, WT_ = EW - 2 * MARGIN;
    constexpr int WP = WT_ / 2, NPAIR = HT_ * WP;
    static_assert(NPAIR <= NT, "single strip required");
    uint4 nq0[GP], nq1[GP];
    bool wr = false;
    int ey = 0, ex0 = 0;
    if (tid < NPAIR) {
        const int pr = tid / WP, pc = tid % WP;
        ey = MARGIN + pr; ex0 = MARGIN + 2 * pc;           // ex0 even
        const int gy = y0 + ey - HALO, gx0 = x0 + ex0 - HALO;  // gx0 even
        if ((unsigned)gy < H && (unsigned)gx0 < W) {       // pair-uniform (gx0 even)
            const uint2 cc0 = simgh[ey * EW + ex0];
            const uint2 cc1 = simgh[ey * EW + ex0 + 1];
            const float3 c0 = dec3(cc0.x, cc0.y);
            const float3 c1 = dec3(cc1.x, cc1.y);
            const __half2 zero2 = __float2half2_rn(0.f);
            __half2 a0[GP][4], a1[GP][4];
#pragma unroll
            for (int g = 0; g < GP; ++g)
#pragma unroll
                for (int j = 0; j < 4; ++j) { a0[g][j] = zero2; a1[g][j] = zero2; }
            row_taps<0>(ey - 2, ex0, simgh, bufQ, c0, c1, a0, a1);
            row_taps<1>(ey - 1, ex0, simgh, bufQ, c0, c1, a0, a1);
            row_taps<2>(ey    , ex0, simgh, bufQ, c0, c1, a0, a1);
            row_taps<3>(ey + 1, ex0, simgh, bufQ, c0, c1, a0, a1);
            row_taps<4>(ey + 2, ex0, simgh, bufQ, c0, c1, a0, a1);
            const float* lgp0 = lgb + gy * W + gx0;
            float* qo0 = outp + (size_t)b * C * HW + gy * W + gx0;
            finish_cell<FINAL>(fast, lgp0,     scm, a0, qo0,     nq0);
            finish_cell<FINAL>(fast, lgp0 + 1, scm, a1, qo0 + 1, nq1);
            wr = !FINAL;
        }
    }
    if (!FINAL) {
        __syncthreads();                 // all reads of old q done
        if (wr) {
#pragma unroll
            for (int g = 0; g < GP; ++g) {
                bufQ[g][ey][ex0]     = nq0[g];
                bufQ[g][ey][ex0 + 1] = nq1[g];
            }
        }
        __syncthreads();                 // new q visible
    }
}

// ---------------------------------------------------------------------------
// Mega-fused CRF: q0 = softmax(logits) staged on a 36x52 extended tile, then
// all 5 mean-field iterations in-LDS with shrinking regions, horizontal-pair
// tap sharing. One dispatch, 256 blocks (1/CU) x 1024 threads. LDS 106.6 KB.
// ---------------------------------------------------------------------------
__global__ __launch_bounds__(NT, 4) void crf_mega(
        const float* __restrict__ logits, const float* __restrict__ img,
        const float* __restrict__ compat, float* __restrict__ out) {
    __shared__ __align__(16) uint4 bufQ[GP][EH][EW];   // 89856 B
    __shared__ __align__(16) uint2 simgh[NEC];         // 14976 B
    __shared__ float scm[C * C];                       // 1764 B

    const int b = blockIdx.z;
    const int x0 = blockIdx.x * TW, y0 = blockIdx.y * TH;
    const int tid = threadIdx.x;

    // ---- compat stage (+ -I check) ----
    int ok = 1;
    for (int i = tid; i < C * C; i += NT) {
        const float v = compat[i];
        scm[i] = v;
        ok &= (v == ((i / C == i % C) ? -1.0f : 0.0f));
    }

    const float* im  = img + (size_t)b * 3 * HW;
    const float* lgb = logits + (size_t)b * C * HW;

    // ---- stage img (packed fp16 rgb) and q0 = softmax(logits) (fp16) ----
    for (int cell = tid; cell < NEC; cell += NT) {
        const int ey = cell / EW, ex = cell % EW;
        const int gy = y0 + ey - HALO, gx = x0 + ex - HALO;
        float ir = 0.f, ig = 0.f, ib = 0.f;
        float vals[24];
        if ((unsigned)gy < H && (unsigned)gx < W) {
            const int np = gy * W + gx;
            ir = im[np]; ig = im[HW + np]; ib = im[2 * HW + np];
            const float* lg = lgb + np;
            float zz[C], mx = -1e30f;
#pragma unroll
            for (int c = 0; c < C; ++c) {
                zz[c] = lg[(size_t)c * HW]; mx = fmaxf(mx, zz[c]);
            }
            float ssum = 0.f;
#pragma unroll
            for (int c = 0; c < C; ++c) { zz[c] = __expf(zz[c] - mx); ssum += zz[c]; }
            const float inv = 1.f / ssum;
#pragma unroll
            for (int c = 0; c < 24; ++c) vals[c] = (c < C) ? zz[c] * inv : 0.f;
        } else {
#pragma unroll
            for (int c = 0; c < 24; ++c) vals[c] = 0.f;
        }
        simgh[cell] = make_uint2(packh2(ir, ig), packh2(ib, 0.f));
#pragma unroll
        for (int g = 0; g < GP; ++g)
            bufQ[g][ey][ex] = make_uint4(
                packh2(vals[8 * g + 0], vals[8 * g + 1]),
                packh2(vals[8 * g + 2], vals[8 * g + 3]),
                packh2(vals[8 * g + 4], vals[8 * g + 5]),
                packh2(vals[8 * g + 6], vals[8 * g + 7]));
    }
    const int fast = __syncthreads_and(ok);

    // ---- 5 fused iterations, shrinking regions (margins 2,4,6,8,10) ----
    mf_iter< 2, false>(tid, b, y0, x0, fast, lgb, scm, bufQ, simgh, out);
    mf_iter< 4, false>(tid, b, y0, x0, fast, lgb, scm, bufQ, simgh, out);
    mf_iter< 6, false>(tid, b, y0, x0, fast, lgb, scm, bufQ, simgh, out);
    mf_iter< 8, false>(tid, b, y0, x0, fast, lgb, scm, bufQ, simgh, out);
    mf_iter<10, true >(tid, b, y0, x0, fast, lgb, scm, bufQ, simgh, out);
}

// ---------------------------------------------------------------------------
extern "C" void kernel_launch(void* const* d_in, const int* in_sizes, int n_in,
                              void* d_out, int out_size, void* d_ws, size_t ws_size,
                              hipStream_t stream) {
    const float* logits = (const float*)d_in[0];
    const float* img    = (const float*)d_in[1];
    // d_in[2] = gt_edges (dead code in reference)
    const float* compat = (const float*)d_in[3];
    float* out = (float*)d_out;

    dim3 g(W / TW, H / TH, Bn);      // 8 x 16 x 2 = 256 blocks = 1 per CU
    crf_mega<<<g, NT, 0, stream>>>(logits, img, compat, out);
}

// Round 19
// 369.113 us; speedup vs baseline: 1.0472x; 1.0472x over previous
//
#include <hip/hip_runtime.h>
#include <hip/hip_fp16.h>

constexpr int Bn = 2, C = 21, H = 256, W = 256, HW = H * W;
constexpr int GP = 3;                       // quad-pairs (8 channels per 16B)
constexpr int TW = 32, TH = 16, NT = 768;   // output tile / block size
constexpr int HALO = 10;                    // 5 iterations x 2-halo
constexpr int EH = TH + 2 * HALO;           // 36
constexpr int EW = TW + 2 * HALO;           // 52
constexpr int COLS = EW / 2;                // 26 (even/odd column split)
constexpr int NEC = EH * EW;                // 1872

// Normalized spatial gaussian (sigma=5): exp(-(dy^2+dx^2)/50)/S, S=23.1036923.
__device__ constexpr float SKN[25] = {
    0.03688346f, 0.03916421f, 0.03995538f, 0.03916421f, 0.03688346f,
    0.03916421f, 0.04158598f, 0.04242608f, 0.04158598f, 0.03916421f,
    0.03995538f, 0.04242608f, 0.04328314f, 0.04242608f, 0.03995538f,
    0.03916421f, 0.04158598f, 0.04242608f, 0.04158598f, 0.03916421f,
    0.03688346f, 0.03916421f, 0.03995538f, 0.03916421f, 0.03688346f};

union H2U { __half2 h; unsigned int u; };

__device__ __forceinline__ unsigned int packh2(float a, float b) {
    H2U u; u.h = __floats2half2_rn(a, b); return u.u;
}
__device__ __forceinline__ float3 dec3(unsigned int urg, unsigned int ubz) {
    H2U a; a.u = urg; const float2 rg = __half22float2(a.h);
    H2U b; b.u = ubz; const float2 bz = __half22float2(b.h);
    return make_float3(rg.x, rg.y, bz.x);
}

// Bilateral weight for kernel row R, col CC vs center c (identity folded at
// the window center: spatial gaussian sigma=0.1 is a delta).
template <int R, int CC>
__device__ __forceinline__ unsigned int wcalc(const float3& p, const float3& c) {
    const float d0 = p.x - c.x, d1 = p.y - c.y, d2 = p.z - c.z;
    float wv = SKN[R * 5 + CC] * __expf(-50.f * (d0 * d0 + d1 * d1 + d2 * d2));
    if (R == 2 && CC == 2) wv += 1.0f;
    return packh2(wv, wv);
}

__device__ __forceinline__ void hfma4(__half2 (&a)[4], unsigned int w,
                                      const uint4& q) {
    H2U wv; wv.u = w;
    H2U q0, q1, q2, q3;
    q0.u = q.x; q1.u = q.y; q2.u = q.z; q3.u = q.w;
    a[0] = __hfma2(wv.h, q0.h, a[0]);
    a[1] = __hfma2(wv.h, q1.h, a[1]);
    a[2] = __hfma2(wv.h, q2.h, a[2]);
    a[3] = __hfma2(wv.h, q3.h, a[3]);
}

// ---------------------------------------------------------------------------
// One tap row (kernel row R) for a horizontal cell pair at column col
// (cells ex0=2*col, ex0+1). Even/odd split: all reads at 16B lane stride.
// ---------------------------------------------------------------------------
template <int R>
__device__ __forceinline__ void row_taps(
        int ly, int col, const uint2* __restrict__ simgh,
        const uint4 (*__restrict__ bufQe)[EH][COLS],
        const uint4 (*__restrict__ bufQo)[EH][COLS],
        const float3& c0, const float3& c1,
        __half2 (&a0)[GP][4], __half2 (&a1)[GP][4]) {
    const int base = ly * EW + 2 * col;
    const uint4 iA = *reinterpret_cast<const uint4*>(simgh + base - 2);
    const uint4 iB = *reinterpret_cast<const uint4*>(simgh + base);
    const uint4 iC = *reinterpret_cast<const uint4*>(simgh + base + 2);
    unsigned int w0[5], w1[5];
    {
        float3 p;
        p = dec3(iA.x, iA.y); w0[0] = wcalc<R, 0>(p, c0);
        p = dec3(iA.z, iA.w); w0[1] = wcalc<R, 1>(p, c0); w1[0] = wcalc<R, 0>(p, c1);
        p = dec3(iB.x, iB.y); w0[2] = wcalc<R, 2>(p, c0); w1[1] = wcalc<R, 1>(p, c1);
        p = dec3(iB.z, iB.w); w0[3] = wcalc<R, 3>(p, c0); w1[2] = wcalc<R, 2>(p, c1);
        p = dec3(iC.x, iC.y); w0[4] = wcalc<R, 4>(p, c0); w1[3] = wcalc<R, 3>(p, c1);
        p = dec3(iC.z, iC.w);                             w1[4] = wcalc<R, 4>(p, c1);
    }
#pragma unroll
    for (int g = 0; g < GP; ++g) {
        const uint4 qe0 = bufQe[g][ly][col - 1];
        const uint4 qo0 = bufQo[g][ly][col - 1];
        const uint4 qe1 = bufQe[g][ly][col];
        const uint4 qo1 = bufQo[g][ly][col];
        const uint4 qe2 = bufQe[g][ly][col + 1];
        const uint4 qo2 = bufQo[g][ly][col + 1];
        hfma4(a0[g], w0[0], qe0);
        hfma4(a0[g], w0[1], qo0);
        hfma4(a0[g], w0[2], qe1);
        hfma4(a0[g], w0[3], qo1);
        hfma4(a0[g], w0[4], qe2);
        hfma4(a1[g], w1[0], qo0);
        hfma4(a1[g], w1[1], qe1);
        hfma4(a1[g], w1[2], qo1);
        hfma4(a1[g], w1[3], qe2);
        hfma4(a1[g], w1[4], qo2);
    }
}

// ---------------------------------------------------------------------------
// Compat + softmax + output for one cell (acc consumed; z[24] transient).
// ---------------------------------------------------------------------------
template <bool FINAL>
__device__ __forceinline__ void finish_cell(
        int fast, const float* __restrict__ lgp, const float* __restrict__ scm,
        const __half2 (&acc)[GP][4], float* __restrict__ qo, uint4 (&nq)[GP]) {
    float z[24];
    if (fast) {                        // compat == -I: z = logits + m
#pragma unroll
        for (int g = 0; g < GP; ++g)
#pragma unroll
            for (int j = 0; j < 4; ++j) {
                const float2 f = __half22float2(acc[g][j]);
                const int c = 8 * g + 2 * j;
                z[c]     = (c     < C) ? lgp[(size_t)c * HW] + f.x       : -1e30f;
                z[c + 1] = (c + 1 < C) ? lgp[(size_t)(c + 1) * HW] + f.y : -1e30f;
            }
    } else {                           // general matvec, thread-local
        float m[24];
#pragma unroll
        for (int g = 0; g < GP; ++g)
#pragma unroll
            for (int j = 0; j < 4; ++j) {
                const float2 f = __half22float2(acc[g][j]);
                m[8 * g + 2 * j + 0] = f.x;
                m[8 * g + 2 * j + 1] = f.y;
            }
#pragma unroll
        for (int c = 0; c < 24; ++c) {
            if (c < C) {
                float pw = 0.f;
#pragma unroll
                for (int j = 0; j < C; ++j) pw += scm[c * C + j] * m[j];
                z[c] = lgp[(size_t)c * HW] - pw;
            } else z[c] = -1e30f;
        }
    }
    float mx = -1e30f;
#pragma unroll
    for (int c = 0; c < C; ++c) mx = fmaxf(mx, z[c]);
    float s = 0.f;
#pragma unroll
    for (int c = 0; c < 24; ++c) {
        z[c] = (c < C) ? __expf(z[c] - mx) : 0.f;
        if (c < C) s += z[c];
    }
    const float inv = 1.f / s;
    if (FINAL) {
#pragma unroll
        for (int c = 0; c < C; ++c) qo[(size_t)c * HW] = z[c] * inv;
    } else {
#pragma unroll
        for (int g = 0; g < GP; ++g)
            nq[g] = make_uint4(
                packh2(z[8 * g + 0] * inv, z[8 * g + 1] * inv),
                packh2(z[8 * g + 2] * inv, z[8 * g + 3] * inv),
                packh2(z[8 * g + 4] * inv, z[8 * g + 5] * inv),
                packh2(z[8 * g + 6] * inv, z[8 * g + 7] * inv));
    }
}

// ---------------------------------------------------------------------------
// One mean-field iteration; horizontal pair per thread. All margins give
// NPAIR <= 768 = NT: single strip, no per-strip arrays.
// ---------------------------------------------------------------------------
template <int MARGIN, bool FINAL>
__device__ __forceinline__ void mf_iter(
        int tid, int b, int y0, int x0, int fast,
        const float* __restrict__ lgb, const float* __restrict__ scm,
        uint4 (*bufQe)[EH][COLS], uint4 (*bufQo)[EH][COLS],
        const uint2* __restrict__ simgh, float* __restrict__ outp) {
    constexpr int HT_ = EH - 2 * MARGIN, WT_ = EW - 2 * MARGIN;
    constexpr int WP = WT_ / 2, NPAIR = HT_ * WP;
    static_assert(NPAIR <= NT, "single strip required");
    uint4 nq0[GP], nq1[GP];
    bool wr = false;
    int ey = 0, col = 0;
    if (tid < NPAIR) {
        const int pr = tid / WP, pc = tid % WP;
        ey = MARGIN + pr;
        const int ex0 = MARGIN + 2 * pc;                   // even
        col = ex0 >> 1;
        const int gy = y0 + ey - HALO, gx0 = x0 + ex0 - HALO;  // gx0 even
        if ((unsigned)gy < H && (unsigned)gx0 < W) {       // pair-uniform
            const uint2 cc0 = simgh[ey * EW + ex0];
            const uint2 cc1 = simgh[ey * EW + ex0 + 1];
            const float3 c0 = dec3(cc0.x, cc0.y);
            const float3 c1 = dec3(cc1.x, cc1.y);
            const __half2 zero2 = __float2half2_rn(0.f);
            __half2 a0[GP][4], a1[GP][4];
#pragma unroll
            for (int g = 0; g < GP; ++g)
#pragma unroll
                for (int j = 0; j < 4; ++j) { a0[g][j] = zero2; a1[g][j] = zero2; }
            row_taps<0>(ey - 2, col, simgh, bufQe, bufQo, c0, c1, a0, a1);
            row_taps<1>(ey - 1, col, simgh, bufQe, bufQo, c0, c1, a0, a1);
            row_taps<2>(ey    , col, simgh, bufQe, bufQo, c0, c1, a0, a1);
            row_taps<3>(ey + 1, col, simgh, bufQe, bufQo, c0, c1, a0, a1);
            row_taps<4>(ey + 2, col, simgh, bufQe, bufQo, c0, c1, a0, a1);
            const float* lgp0 = lgb + gy * W + gx0;
            float* qo0 = outp + (size_t)b * C * HW + gy * W + gx0;
            finish_cell<FINAL>(fast, lgp0,     scm, a0, qo0,     nq0);
            finish_cell<FINAL>(fast, lgp0 + 1, scm, a1, qo0 + 1, nq1);
            wr = !FINAL;
        }
    }
    if (!FINAL) {
        __syncthreads();                 // all reads of old q done
        if (wr) {
#pragma unroll
            for (int g = 0; g < GP; ++g) {
                bufQe[g][ey][col] = nq0[g];
                bufQo[g][ey][col] = nq1[g];
            }
        }
        __syncthreads();                 // new q visible
    }
}

// ---------------------------------------------------------------------------
// Mega-fused CRF: q0 = softmax(logits) staged on a 36x52 extended tile, then
// all 5 mean-field iterations in-LDS (shrinking regions, horizontal-pair tap
// sharing, even/odd column split). 256 blocks (1/CU) x 768 threads (12 waves,
// 3/EU pinned -> VGPR budget well above the NT=1024 64-reg wall). LDS 106.6KB.
// ---------------------------------------------------------------------------
__global__ __launch_bounds__(NT)
__attribute__((amdgpu_waves_per_eu(3, 3)))
void crf_mega(
        const float* __restrict__ logits, const float* __restrict__ img,
        const float* __restrict__ compat, float* __restrict__ out) {
    __shared__ __align__(16) uint4 bufQe[GP][EH][COLS];  // 44928 B
    __shared__ __align__(16) uint4 bufQo[GP][EH][COLS];  // 44928 B
    __shared__ __align__(16) uint2 simgh[NEC];           // 14976 B
    __shared__ float scm[C * C];                         // 1764 B

    const int b = blockIdx.z;
    const int x0 = blockIdx.x * TW, y0 = blockIdx.y * TH;
    const int tid = threadIdx.x;

    // ---- compat stage (+ -I check) ----
    int ok = 1;
    for (int i = tid; i < C * C; i += NT) {
        const float v = compat[i];
        scm[i] = v;
        ok &= (v == ((i / C == i % C) ? -1.0f : 0.0f));
    }

    const float* im  = img + (size_t)b * 3 * HW;
    const float* lgb = logits + (size_t)b * C * HW;

    // ---- stage img (packed fp16 rgb) and q0 = softmax(logits) (fp16) ----
    for (int cell = tid; cell < NEC; cell += NT) {
        const int ey = cell / EW, ex = cell % EW;
        const int gy = y0 + ey - HALO, gx = x0 + ex - HALO;
        float ir = 0.f, ig = 0.f, ib = 0.f;
        float vals[24];
        if ((unsigned)gy < H && (unsigned)gx < W) {
            const int np = gy * W + gx;
            ir = im[np]; ig = im[HW + np]; ib = im[2 * HW + np];
            const float* lg = lgb + np;
            float zz[C], mx = -1e30f;
#pragma unroll
            for (int c = 0; c < C; ++c) {
                zz[c] = lg[(size_t)c * HW]; mx = fmaxf(mx, zz[c]);
            }
            float ssum = 0.f;
#pragma unroll
            for (int c = 0; c < C; ++c) { zz[c] = __expf(zz[c] - mx); ssum += zz[c]; }
            const float inv = 1.f / ssum;
#pragma unroll
            for (int c = 0; c < 24; ++c) vals[c] = (c < C) ? zz[c] * inv : 0.f;
        } else {
#pragma unroll
            for (int c = 0; c < 24; ++c) vals[c] = 0.f;
        }
        simgh[cell] = make_uint2(packh2(ir, ig), packh2(ib, 0.f));
        uint4* dst = (ex & 1) ? &bufQo[0][ey][ex >> 1] : &bufQe[0][ey][ex >> 1];
#pragma unroll
        for (int g = 0; g < GP; ++g)
            dst[g * EH * COLS] = make_uint4(
                packh2(vals[8 * g + 0], vals[8 * g + 1]),
                packh2(vals[8 * g + 2], vals[8 * g + 3]),
                packh2(vals[8 * g + 4], vals[8 * g + 5]),
                packh2(vals[8 * g + 6], vals[8 * g + 7]));
    }
    const int fast = __syncthreads_and(ok);

    // ---- 5 fused iterations, shrinking regions (margins 2,4,6,8,10) ----
    mf_iter< 2, false>(tid, b, y0, x0, fast, lgb, scm, bufQe, bufQo, simgh, out);
    mf_iter< 4, false>(tid, b, y0, x0, fast, lgb, scm, bufQe, bufQo, simgh, out);
    mf_iter< 6, false>(tid, b, y0, x0, fast, lgb, scm, bufQe, bufQo, simgh, out);
    mf_iter< 8, false>(tid, b, y0, x0, fast, lgb, scm, bufQe, bufQo, simgh, out);
    mf_iter<10, true >(tid, b, y0, x0, fast, lgb, scm, bufQe, bufQo, simgh, out);
}

// ---------------------------------------------------------------------------
extern "C" void kernel_launch(void* const* d_in, const int* in_sizes, int n_in,
                              void* d_out, int out_size, void* d_ws, size_t ws_size,
                              hipStream_t stream) {
    const float* logits = (const float*)d_in[0];
    const float* img    = (const float*)d_in[1];
    // d_in[2] = gt_edges (dead code in reference)
    const float* compat = (const float*)d_in[3];
    float* out = (float*)d_out;

    dim3 g(W / TW, H / TH, Bn);      // 8 x 16 x 2 = 256 blocks = 1 per CU
    crf_mega<<<g, NT, 0, stream>>>(logits, img, compat, out);
}

// Round 20
// 346.934 us; speedup vs baseline: 1.1141x; 1.0639x over previous
//
#include <hip/hip_runtime.h>
#include <hip/hip_fp16.h>

constexpr int Bn = 2, C = 21, H = 256, W = 256, HW = H * W;
constexpr int GP = 3;                       // quad-pairs (8 channels per 16B)
constexpr int TW = 32, TH = 16, NT = 768;   // output tile / block size
constexpr int HALO = 10;                    // 5 iterations x 2-halo
constexpr int EH = TH + 2 * HALO;           // 36
constexpr int EW = TW + 2 * HALO;           // 52
constexpr int NEC = EH * EW;                // 1872

// Normalized spatial gaussian (sigma=5): exp(-(dy^2+dx^2)/50)/S, S=23.1036923.
__device__ constexpr float SKN[25] = {
    0.03688346f, 0.03916421f, 0.03995538f, 0.03916421f, 0.03688346f,
    0.03916421f, 0.04158598f, 0.04242608f, 0.04158598f, 0.03916421f,
    0.03995538f, 0.04242608f, 0.04328314f, 0.04242608f, 0.03995538f,
    0.03916421f, 0.04158598f, 0.04242608f, 0.04158598f, 0.03916421f,
    0.03688346f, 0.03916421f, 0.03995538f, 0.03916421f, 0.03688346f};

union H2U { __half2 h; unsigned int u; };

__device__ __forceinline__ unsigned int packh2(float a, float b) {
    H2U u; u.h = __floats2half2_rn(a, b); return u.u;
}
__device__ __forceinline__ float3 dec3(unsigned int urg, unsigned int ubz) {
    H2U a; a.u = urg; const float2 rg = __half22float2(a.h);
    H2U b; b.u = ubz; const float2 bz = __half22float2(b.h);
    return make_float3(rg.x, rg.y, bz.x);
}
__device__ __forceinline__ void hfma4(__half2 (&a)[4], unsigned int w,
                                      const uint4& q) {
    H2U wv; wv.u = w;
    H2U q0, q1, q2, q3;
    q0.u = q.x; q1.u = q.y; q2.u = q.z; q3.u = q.w;
    a[0] = __hfma2(wv.h, q0.h, a[0]);
    a[1] = __hfma2(wv.h, q1.h, a[1]);
    a[2] = __hfma2(wv.h, q2.h, a[2]);
    a[3] = __hfma2(wv.h, q3.h, a[3]);
}

// ---------------------------------------------------------------------------
// Compat + softmax + output for one cell (R17's proven finish, unchanged).
// ---------------------------------------------------------------------------
template <bool FINAL>
__device__ __forceinline__ void finish_cell(
        int fast, const float* __restrict__ lgp, const float* __restrict__ scm,
        const __half2 (&acc)[GP][4], float* __restrict__ qo, uint4 (&nq)[GP]) {
    float z[24];
    if (fast) {                        // compat == -I: z = logits + m
#pragma unroll
        for (int g = 0; g < GP; ++g)
#pragma unroll
            for (int j = 0; j < 4; ++j) {
                const float2 f = __half22float2(acc[g][j]);
                const int c = 8 * g + 2 * j;
                z[c]     = (c     < C) ? lgp[(size_t)c * HW] + f.x       : -1e30f;
                z[c + 1] = (c + 1 < C) ? lgp[(size_t)(c + 1) * HW] + f.y : -1e30f;
            }
    } else {                           // general matvec, thread-local
        float m[24];
#pragma unroll
        for (int g = 0; g < GP; ++g)
#pragma unroll
            for (int j = 0; j < 4; ++j) {
                const float2 f = __half22float2(acc[g][j]);
                m[8 * g + 2 * j + 0] = f.x;
                m[8 * g + 2 * j + 1] = f.y;
            }
#pragma unroll
        for (int c = 0; c < 24; ++c) {
            if (c < C) {
                float pw = 0.f;
#pragma unroll
                for (int j = 0; j < C; ++j) pw += scm[c * C + j] * m[j];
                z[c] = lgp[(size_t)c * HW] - pw;
            } else z[c] = -1e30f;
        }
    }
    float mx = -1e30f;
#pragma unroll
    for (int c = 0; c < C; ++c) mx = fmaxf(mx, z[c]);
    float s = 0.f;
#pragma unroll
    for (int c = 0; c < 24; ++c) {
        z[c] = (c < C) ? __expf(z[c] - mx) : 0.f;
        if (c < C) s += z[c];
    }
    const float inv = 1.f / s;
    if (FINAL) {
#pragma unroll
        for (int c = 0; c < C; ++c) qo[(size_t)c * HW] = z[c] * inv;
    } else {
#pragma unroll
        for (int g = 0; g < GP; ++g)
            nq[g] = make_uint4(
                packh2(z[8 * g + 0] * inv, z[8 * g + 1] * inv),
                packh2(z[8 * g + 2] * inv, z[8 * g + 3] * inv),
                packh2(z[8 * g + 4] * inv, z[8 * g + 5] * inv),
                packh2(z[8 * g + 6] * inv, z[8 * g + 7] * inv));
    }
}

// ---------------------------------------------------------------------------
// One mean-field iteration; VERTICAL cell pair (ey0, ey0+1) per thread.
// 6 tap rows x 5 cols streamed once; q (3 b128) + img (1 b64) per position
// serve both cells (45 q-reads/cell vs 75). Inner live set mirrors R17.
// Pair validity is uniform: ey0 even & y0 mult of 16 => gy0 even.
// ---------------------------------------------------------------------------
template <int MARGIN, bool FINAL>
__device__ __forceinline__ void mf_iter(
        int tid, int b, int y0, int x0, int fast,
        const float* __restrict__ lgb, const float* __restrict__ scm,
        uint4 (*bufQ)[EH][EW], const uint2* __restrict__ simgh,
        float* __restrict__ outp) {
    constexpr int HT_ = EH - 2 * MARGIN, WT_ = EW - 2 * MARGIN;
    constexpr int NP = WT_ * (HT_ / 2);   // HT_ always even
    static_assert(NP <= NT, "single strip required");
    uint4 nq0[GP], nq1[GP];
    bool wr = false;
    int ey0 = 0, ex = 0;
    if (tid < NP) {
        const int pr = tid / WT_, pc = tid % WT_;
        ey0 = MARGIN + 2 * pr;                      // even
        ex = MARGIN + pc;
        const int gy0 = y0 + ey0 - HALO, gx = x0 + ex - HALO;  // gy0 even
        if ((unsigned)gy0 < H && (unsigned)gx < W) {           // pair-uniform
            const uint2 cc0 = simgh[ey0 * EW + ex];
            const uint2 cc1 = simgh[(ey0 + 1) * EW + ex];
            const float3 c0 = dec3(cc0.x, cc0.y);
            const float3 c1 = dec3(cc1.x, cc1.y);
            const __half2 zero2 = __float2half2_rn(0.f);
            __half2 a0[GP][4], a1[GP][4];
#pragma unroll
            for (int g = 0; g < GP; ++g)
#pragma unroll
                for (int j = 0; j < 4; ++j) { a0[g][j] = zero2; a1[g][j] = zero2; }
#pragma unroll
            for (int lyo = 0; lyo < 6; ++lyo) {
                const int ly = ey0 - 2 + lyo;
#pragma unroll
                for (int lxo = 0; lxo < 5; ++lxo) {
                    const int lx = ex - 2 + lxo;
                    const uint2 ip = simgh[ly * EW + lx];
                    const float3 p = dec3(ip.x, ip.y);
                    const uint4 q0 = bufQ[0][ly][lx];
                    const uint4 q1 = bufQ[1][ly][lx];
                    const uint4 q2 = bufQ[2][ly][lx];
                    if (lyo <= 4) {                 // cell0 tap row lyo
                        const float d0 = p.x - c0.x, d1 = p.y - c0.y,
                                    d2 = p.z - c0.z;
                        float wv = SKN[lyo * 5 + lxo] *
                            __expf(-50.f * (d0 * d0 + d1 * d1 + d2 * d2));
                        if (lyo == 2 && lxo == 2) wv += 1.0f;  // delta conv
                        const unsigned int w = packh2(wv, wv);
                        hfma4(a0[0], w, q0);
                        hfma4(a0[1], w, q1);
                        hfma4(a0[2], w, q2);
                    }
                    if (lyo >= 1) {                 // cell1 tap row lyo-1
                        const float d0 = p.x - c1.x, d1 = p.y - c1.y,
                                    d2 = p.z - c1.z;
                        float wv = SKN[(lyo - 1) * 5 + lxo] *
                            __expf(-50.f * (d0 * d0 + d1 * d1 + d2 * d2));
                        if (lyo == 3 && lxo == 2) wv += 1.0f;  // (lyo-1)==2
                        const unsigned int w = packh2(wv, wv);
                        hfma4(a1[0], w, q0);
                        hfma4(a1[1], w, q1);
                        hfma4(a1[2], w, q2);
                    }
                }
            }
            const float* lgp0 = lgb + gy0 * W + gx;
            float* qo0 = outp + (size_t)b * C * HW + gy0 * W + gx;
            finish_cell<FINAL>(fast, lgp0,     scm, a0, qo0,     nq0);
            finish_cell<FINAL>(fast, lgp0 + W, scm, a1, qo0 + W, nq1);
            wr = !FINAL;
        }
    }
    if (!FINAL) {
        __syncthreads();                 // all reads of old q done
        if (wr) {
#pragma unroll
            for (int g = 0; g < GP; ++g) {
                bufQ[g][ey0][ex]     = nq0[g];
                bufQ[g][ey0 + 1][ex] = nq1[g];
            }
        }
        __syncthreads();                 // new q visible
    }
}

// ---------------------------------------------------------------------------
// Mega-fused CRF: q0 = softmax(logits) staged on a 36x52 extended tile, then
// all 5 mean-field iterations in-LDS (shrinking regions, vertical-pair tap
// sharing). 256 blocks (1/CU) x 768 threads (12 waves, 3/EU). LDS 106.6 KB.
// ---------------------------------------------------------------------------
__global__ __launch_bounds__(NT)
__attribute__((amdgpu_waves_per_eu(3, 3)))
void crf_mega(
        const float* __restrict__ logits, const float* __restrict__ img,
        const float* __restrict__ compat, float* __restrict__ out) {
    __shared__ __align__(16) uint4 bufQ[GP][EH][EW];   // 89856 B
    __shared__ __align__(16) uint2 simgh[NEC];         // 14976 B
    __shared__ float scm[C * C];                       // 1764 B

    const int b = blockIdx.z;
    const int x0 = blockIdx.x * TW, y0 = blockIdx.y * TH;
    const int tid = threadIdx.x;

    // ---- compat stage (+ -I check) ----
    int ok = 1;
    for (int i = tid; i < C * C; i += NT) {
        const float v = compat[i];
        scm[i] = v;
        ok &= (v == ((i / C == i % C) ? -1.0f : 0.0f));
    }

    const float* im  = img + (size_t)b * 3 * HW;
    const float* lgb = logits + (size_t)b * C * HW;

    // ---- stage img (packed fp16 rgb) and q0 = softmax(logits) (fp16) ----
    for (int cell = tid; cell < NEC; cell += NT) {
        const int ey = cell / EW, ex = cell % EW;
        const int gy = y0 + ey - HALO, gx = x0 + ex - HALO;
        float ir = 0.f, ig = 0.f, ib = 0.f;
        float vals[24];
        if ((unsigned)gy < H && (unsigned)gx < W) {
            const int np = gy * W + gx;
            ir = im[np]; ig = im[HW + np]; ib = im[2 * HW + np];
            const float* lg = lgb + np;
            float zz[C], mx = -1e30f;
#pragma unroll
            for (int c = 0; c < C; ++c) {
                zz[c] = lg[(size_t)c * HW]; mx = fmaxf(mx, zz[c]);
            }
            float ssum = 0.f;
#pragma unroll
            for (int c = 0; c < C; ++c) { zz[c] = __expf(zz[c] - mx); ssum += zz[c]; }
            const float inv = 1.f / ssum;
#pragma unroll
            for (int c = 0; c < 24; ++c) vals[c] = (c < C) ? zz[c] * inv : 0.f;
        } else {
#pragma unroll
            for (int c = 0; c < 24; ++c) vals[c] = 0.f;
        }
        simgh[cell] = make_uint2(packh2(ir, ig), packh2(ib, 0.f));
#pragma unroll
        for (int g = 0; g < GP; ++g)
            bufQ[g][ey][ex] = make_uint4(
                packh2(vals[8 * g + 0], vals[8 * g + 1]),
                packh2(vals[8 * g + 2], vals[8 * g + 3]),
                packh2(vals[8 * g + 4], vals[8 * g + 5]),
                packh2(vals[8 * g + 6], vals[8 * g + 7]));
    }
    const int fast = __syncthreads_and(ok);

    // ---- 5 fused iterations, shrinking regions (margins 2,4,6,8,10) ----
    mf_iter< 2, false>(tid, b, y0, x0, fast, lgb, scm, bufQ, simgh, out);
    mf_iter< 4, false>(tid, b, y0, x0, fast, lgb, scm, bufQ, simgh, out);
    mf_iter< 6, false>(tid, b, y0, x0, fast, lgb, scm, bufQ, simgh, out);
    mf_iter< 8, false>(tid, b, y0, x0, fast, lgb, scm, bufQ, simgh, out);
    mf_iter<10, true >(tid, b, y0, x0, fast, lgb, scm, bufQ, simgh, out);
}

// ---------------------------------------------------------------------------
extern "C" void kernel_launch(void* const* d_in, const int* in_sizes, int n_in,
                              void* d_out, int out_size, void* d_ws, size_t ws_size,
                              hipStream_t stream) {
    const float* logits = (const float*)d_in[0];
    const float* img    = (const float*)d_in[1];
    // d_in[2] = gt_edges (dead code in reference)
    const float* compat = (const float*)d_in[3];
    float* out = (float*)d_out;

    dim3 g(W / TW, H / TH, Bn);      // 8 x 16 x 2 = 256 blocks = 1 per CU
    crf_mega<<<g, NT, 0, stream>>>(logits, img, compat, out);
}

// Round 21
// 52.926 us; speedup vs baseline: 7.3033x; 6.5551x over previous
//
#include <hip/hip_runtime.h>
#include <hip/hip_fp16.h>

constexpr int Bn = 2, C = 21, H = 256, W = 256, HW = H * W;
constexpr int GP = 3;                       // quad-pairs (8 channels per 16B)
constexpr int TW = 32, TH = 16, NT = 1024;  // output tile / block size
constexpr int HALO = 10;                    // 5 iterations x 2-halo
constexpr int EH = TH + 2 * HALO;           // 36
constexpr int EW = TW + 2 * HALO;           // 52
constexpr int NEC = EH * EW;                // 1872

// Normalized spatial gaussian (sigma=5): exp(-(dy^2+dx^2)/50)/S, S=23.1036923.
__device__ constexpr float SKN[25] = {
    0.03688346f, 0.03916421f, 0.03995538f, 0.03916421f, 0.03688346f,
    0.03916421f, 0.04158598f, 0.04242608f, 0.04158598f, 0.03916421f,
    0.03995538f, 0.04242608f, 0.04328314f, 0.04242608f, 0.03995538f,
    0.03916421f, 0.04158598f, 0.04242608f, 0.04158598f, 0.03916421f,
    0.03688346f, 0.03916421f, 0.03995538f, 0.03916421f, 0.03688346f};

union H2U { __half2 h; unsigned int u; };

__device__ __forceinline__ unsigned int packh2(float a, float b) {
    H2U u; u.h = __floats2half2_rn(a, b); return u.u;
}

// ---------------------------------------------------------------------------
// One mean-field iteration over the shrinking region (margin cells from the
// extended-tile edge). R11's cell body with quad-paired b128 LDS layout.
// ---------------------------------------------------------------------------
template <int MARGIN, bool FINAL>
__device__ __forceinline__ void mf_iter(
        int tid, int b, int y0, int x0, int fast,
        const float* __restrict__ lgb, const float* __restrict__ scm,
        uint4 (*bufQ)[EH][EW], const uint2* __restrict__ simgh,
        float* __restrict__ outp) {
    constexpr int HT_ = EH - 2 * MARGIN, WT_ = EW - 2 * MARGIN;
    constexpr int NCEL = HT_ * WT_;
    constexpr int NS = (NCEL + NT - 1) / NT;
    uint4 nq[NS][GP];
    bool valid[NS];
#pragma unroll
    for (int s = 0; s < NS; ++s) {
        valid[s] = false;
        const int cell = tid + s * NT;
        if (cell < NCEL) {
            const int ry = cell / WT_, rx = cell % WT_;
            const int ey = MARGIN + ry, ex = MARGIN + rx;
            const int gy = y0 + ey - HALO, gx = x0 + ex - HALO;
            if ((unsigned)gy < H && (unsigned)gx < W) {
                valid[s] = true;
                // ---- logits (issued early, hidden under the exp chain) ----
                const float* lgp = lgb + gy * W + gx;
                float lg[C];
#pragma unroll
                for (int c = 0; c < C; ++c) lg[c] = lgp[(size_t)c * HW];
                // ---- bilateral weights from fp16 LDS img tile ----
                float cr, cg, cb;
                {
                    const uint2 cc2 = simgh[ey * EW + ex];
                    H2U a; a.u = cc2.x; const float2 rg = __half22float2(a.h);
                    H2U d; d.u = cc2.y; const float2 bz = __half22float2(d.h);
                    cr = rg.x; cg = rg.y; cb = bz.x;
                }
                unsigned int wk[25];
#pragma unroll
                for (int k = 0; k < 25; ++k) {
                    const int dy = k / 5 - 2, dx = k % 5 - 2;
                    const uint2 n2 = simgh[(ey + dy) * EW + (ex + dx)];
                    H2U a; a.u = n2.x; const float2 rg = __half22float2(a.h);
                    H2U d; d.u = n2.y; const float2 bz = __half22float2(d.h);
                    const float d0 = rg.x - cr, d1 = rg.y - cg, d2 = bz.x - cb;
                    float wv = SKN[k] *
                        __expf(-50.f * (d0 * d0 + d1 * d1 + d2 * d2));
                    if (k == 12) wv += 1.0f;   // identity (delta) spatial conv
                    wk[k] = packh2(wv, wv);
                }
                // ---- 25 taps x 3 b128 quad-pair reads, fp16 A/B partials ---
                const __half2 zero2 = __float2half2_rn(0.f);
                __half2 aA[GP][4], aB[GP][4];
#pragma unroll
                for (int g = 0; g < GP; ++g)
#pragma unroll
                    for (int j = 0; j < 4; ++j) { aA[g][j] = zero2; aB[g][j] = zero2; }
#pragma unroll
                for (int k = 0; k < 25; ++k) {
                    const int ly = ey + k / 5 - 2, lx = ex + k % 5 - 2;
                    H2U wv; wv.u = wk[k];
#pragma unroll
                    for (int g = 0; g < GP; ++g) {
                        const uint4 raw = bufQ[g][ly][lx];
                        H2U q0, q1, q2, q3;
                        q0.u = raw.x; q1.u = raw.y; q2.u = raw.z; q3.u = raw.w;
                        if (k < 13) {
                            aA[g][0] = __hfma2(wv.h, q0.h, aA[g][0]);
                            aA[g][1] = __hfma2(wv.h, q1.h, aA[g][1]);
                            aA[g][2] = __hfma2(wv.h, q2.h, aA[g][2]);
                            aA[g][3] = __hfma2(wv.h, q3.h, aA[g][3]);
                        } else {
                            aB[g][0] = __hfma2(wv.h, q0.h, aB[g][0]);
                            aB[g][1] = __hfma2(wv.h, q1.h, aB[g][1]);
                            aB[g][2] = __hfma2(wv.h, q2.h, aB[g][2]);
                            aB[g][3] = __hfma2(wv.h, q3.h, aB[g][3]);
                        }
                    }
                }
                float m[24];
#pragma unroll
                for (int g = 0; g < GP; ++g)
#pragma unroll
                    for (int j = 0; j < 4; ++j) {
                        const float2 fA = __half22float2(aA[g][j]);
                        const float2 fB = __half22float2(aB[g][j]);
                        m[8 * g + 2 * j + 0] = fA.x + fB.x;
                        m[8 * g + 2 * j + 1] = fA.y + fB.y;
                    }
                // ---- compatibility + softmax (thread-local) ----
                float z[C], mx = -1e30f;
                if (fast) {                  // compat == -I: z = logits + m
#pragma unroll
                    for (int c = 0; c < C; ++c) {
                        z[c] = lg[c] + m[c]; mx = fmaxf(mx, z[c]);
                    }
                } else {                     // general matvec, local
#pragma unroll
                    for (int c = 0; c < C; ++c) {
                        float pw = 0.f;
#pragma unroll
                        for (int j = 0; j < C; ++j) pw += scm[c * C + j] * m[j];
                        z[c] = lg[c] - pw; mx = fmaxf(mx, z[c]);
                    }
                }
                float ssum = 0.f;
#pragma unroll
                for (int c = 0; c < C; ++c) {
                    z[c] = __expf(z[c] - mx); ssum += z[c];
                }
                const float inv = 1.f / ssum;
                if (FINAL) {
                    float* qo = outp + (size_t)b * C * HW + gy * W + gx;
#pragma unroll
                    for (int c = 0; c < C; ++c) qo[(size_t)c * HW] = z[c] * inv;
                } else {
                    float vals[24];
#pragma unroll
                    for (int c = 0; c < 24; ++c)
                        vals[c] = (c < C) ? z[c] * inv : 0.f;
#pragma unroll
                    for (int g = 0; g < GP; ++g)
                        nq[s][g] = make_uint4(
                            packh2(vals[8 * g + 0], vals[8 * g + 1]),
                            packh2(vals[8 * g + 2], vals[8 * g + 3]),
                            packh2(vals[8 * g + 4], vals[8 * g + 5]),
                            packh2(vals[8 * g + 6], vals[8 * g + 7]));
                }
            }
        }
    }
    if (!FINAL) {
        __syncthreads();                     // all reads of old q done
#pragma unroll
        for (int s = 0; s < NS; ++s) {
            if (valid[s]) {
                const int cell = tid + s * NT;
                const int ry = cell / WT_, rx = cell % WT_;
                const int ey = MARGIN + ry, ex = MARGIN + rx;
#pragma unroll
                for (int g = 0; g < GP; ++g) bufQ[g][ey][ex] = nq[s][g];
            }
        }
        __syncthreads();                     // new q visible
    }
}

// ---------------------------------------------------------------------------
// Mega-fused CRF: q0 = softmax(logits) staged on a 36x52 extended tile, then
// all 5 mean-field iterations in-LDS with shrinking regions. One dispatch,
// 256 blocks (1/CU) x 1024 threads. LDS = 106.6 KB (quad-paired q + fp16 img).
// ---------------------------------------------------------------------------
__global__ __launch_bounds__(NT, 4) void crf_mega(
        const float* __restrict__ logits, const float* __restrict__ img,
        const float* __restrict__ compat, float* __restrict__ out) {
    __shared__ __align__(16) uint4 bufQ[GP][EH][EW];   // 89856 B
    __shared__ __align__(16) uint2 simgh[NEC];         // 14976 B
    __shared__ float scm[C * C];                       // 1764 B

    const int b = blockIdx.z;
    const int x0 = blockIdx.x * TW, y0 = blockIdx.y * TH;
    const int tid = threadIdx.x;

    // ---- compat stage (+ -I check) ----
    int ok = 1;
    for (int i = tid; i < C * C; i += NT) {
        const float v = compat[i];
        scm[i] = v;
        ok &= (v == ((i / C == i % C) ? -1.0f : 0.0f));
    }

    const float* im  = img + (size_t)b * 3 * HW;
    const float* lgb = logits + (size_t)b * C * HW;

    // ---- stage img (packed fp16 rgb) and q0 = softmax(logits) (fp16) ----
    for (int cell = tid; cell < NEC; cell += NT) {
        const int ey = cell / EW, ex = cell % EW;
        const int gy = y0 + ey - HALO, gx = x0 + ex - HALO;
        float ir = 0.f, ig = 0.f, ib = 0.f;
        float vals[24];
        if ((unsigned)gy < H && (unsigned)gx < W) {
            const int np = gy * W + gx;
            ir = im[np]; ig = im[HW + np]; ib = im[2 * HW + np];
            const float* lg = lgb + np;
            float zz[C], mx = -1e30f;
#pragma unroll
            for (int c = 0; c < C; ++c) {
                zz[c] = lg[(size_t)c * HW]; mx = fmaxf(mx, zz[c]);
            }
            float ssum = 0.f;
#pragma unroll
            for (int c = 0; c < C; ++c) { zz[c] = __expf(zz[c] - mx); ssum += zz[c]; }
            const float inv = 1.f / ssum;
#pragma unroll
            for (int c = 0; c < 24; ++c) vals[c] = (c < C) ? zz[c] * inv : 0.f;
        } else {
#pragma unroll
            for (int c = 0; c < 24; ++c) vals[c] = 0.f;
        }
        simgh[cell] = make_uint2(packh2(ir, ig), packh2(ib, 0.f));
#pragma unroll
        for (int g = 0; g < GP; ++g)
            bufQ[g][ey][ex] = make_uint4(
                packh2(vals[8 * g + 0], vals[8 * g + 1]),
                packh2(vals[8 * g + 2], vals[8 * g + 3]),
                packh2(vals[8 * g + 4], vals[8 * g + 5]),
                packh2(vals[8 * g + 6], vals[8 * g + 7]));
    }
    const int fast = __syncthreads_and(ok);

    // ---- 5 fused iterations, shrinking regions (margins 2,4,6,8,10) ----
    mf_iter< 2, false>(tid, b, y0, x0, fast, lgb, scm, bufQ, simgh, out);
    mf_iter< 4, false>(tid, b, y0, x0, fast, lgb, scm, bufQ, simgh, out);
    mf_iter< 6, false>(tid, b, y0, x0, fast, lgb, scm, bufQ, simgh, out);
    mf_iter< 8, false>(tid, b, y0, x0, fast, lgb, scm, bufQ, simgh, out);
    mf_iter<10, true >(tid, b, y0, x0, fast, lgb, scm, bufQ, simgh, out);
}

// ---------------------------------------------------------------------------
extern "C" void kernel_launch(void* const* d_in, const int* in_sizes, int n_in,
                              void* d_out, int out_size, void* d_ws, size_t ws_size,
                              hipStream_t stream) {
    const float* logits = (const float*)d_in[0];
    const float* img    = (const float*)d_in[1];
    // d_in[2] = gt_edges (dead code in reference)
    const float* compat = (const float*)d_in[3];
    float* out = (float*)d_out;

    dim3 g(W / TW, H / TH, Bn);      // 8 x 16 x 2 = 256 blocks = 1 per CU
    crf_mega<<<g, NT, 0, stream>>>(logits, img, compat, out);
}